// Round 1
// baseline (664.667 us; speedup 1.0000x reference)
//
#include <hip/hip_runtime.h>

typedef __attribute__((ext_vector_type(8))) short bf16x8;
typedef __attribute__((ext_vector_type(4))) short bf16x4;
typedef __attribute__((ext_vector_type(4))) float f32x4;

__device__ __forceinline__ unsigned short f2bf(float x){
  unsigned u = __float_as_uint(x);
  u = (u + 0x7fffu + ((u >> 16) & 1u)) >> 16;
  return (unsigned short)u;
}

// ---------------- Bjorck (polar factor) small kernels ----------------

// sum of squares of weight (131072 floats), atomic into *n2 (pre-zeroed)
__global__ __launch_bounds__(256) void knorm(const float* __restrict__ wt, float* __restrict__ n2){
  int t = blockIdx.x * 256 + threadIdx.x;
  float4 v = reinterpret_cast<const float4*>(wt)[t];
  float s = v.x*v.x + v.y*v.y + v.z*v.z + v.w*v.w;
  #pragma unroll
  for (int o = 32; o > 0; o >>= 1) s += __shfl_down(s, o, 64);
  __shared__ float red[4];
  if ((threadIdx.x & 63) == 0) red[threadIdx.x >> 6] = s;
  __syncthreads();
  if (threadIdx.x == 0) atomicAdd(n2, red[0] + red[1] + red[2] + red[3]);
}

// W[r][c] = weight[c][r] / (0.3 * ||weight||_F)   (W is 512x256 row-major)
__global__ __launch_bounds__(256) void kinit(const float* __restrict__ wt, const float* __restrict__ n2,
                                             float* __restrict__ W){
  int c = blockIdx.x;      // 0..255
  int r = threadIdx.x;     // 0..255 (+256)
  float s = rsqrtf(*n2) * (1.0f / 0.3f);
  W[(size_t)r * 256 + c]         = wt[(size_t)c * 512 + r] * s;
  W[(size_t)(r + 256) * 256 + c] = wt[(size_t)c * 512 + r + 256] * s;
}

// G = W^T W  (256x256), thread-per-output, grid (16,16)
__global__ __launch_bounds__(256) void kgram(const float* __restrict__ W, float* __restrict__ G){
  int tx = threadIdx.x & 15, ty = threadIdx.x >> 4;
  int j = blockIdx.x * 16 + tx;
  int i = blockIdx.y * 16 + ty;
  float acc = 0.f;
  #pragma unroll 4
  for (int r = 0; r < 512; ++r)
    acc = fmaf(W[r * 256 + i], W[r * 256 + j], acc);
  G[i * 256 + j] = acc;
}

// W <- ca*W + cb*(W G) + cc*(W G) G   (per-row independent; block = 4 rows)
// if last: also emit WT2 in k-tiled bf16 layout [(r/8)*256 + c]*8 + r%8
__global__ __launch_bounds__(256) void kupdate(float* __restrict__ W, const float* __restrict__ G,
    float ca, float cb, float cc, int last, unsigned short* __restrict__ WT2){
  __shared__ float tl[4][256];
  int c = threadIdx.x;
  int r0 = blockIdx.x * 4;
  float y0 = 0, y1 = 0, y2 = 0, y3 = 0;
  #pragma unroll 2
  for (int k = 0; k < 256; ++k){
    float g = G[k * 256 + c];
    y0 = fmaf(W[(r0 + 0) * 256 + k], g, y0);
    y1 = fmaf(W[(r0 + 1) * 256 + k], g, y1);
    y2 = fmaf(W[(r0 + 2) * 256 + k], g, y2);
    y3 = fmaf(W[(r0 + 3) * 256 + k], g, y3);
  }
  tl[0][c] = y0; tl[1][c] = y1; tl[2][c] = y2; tl[3][c] = y3;
  __syncthreads();
  float d0 = 0, d1 = 0, d2 = 0, d3 = 0;
  #pragma unroll 2
  for (int k = 0; k < 256; ++k){
    float g = G[k * 256 + c];
    d0 = fmaf(tl[0][k], g, d0);
    d1 = fmaf(tl[1][k], g, d1);
    d2 = fmaf(tl[2][k], g, d2);
    d3 = fmaf(tl[3][k], g, d3);
  }
  float yv[4] = {y0, y1, y2, y3}, dv[4] = {d0, d1, d2, d3};
  #pragma unroll
  for (int rr = 0; rr < 4; ++rr){
    int r = r0 + rr;
    float nw = ca * W[r * 256 + c] + cb * yv[rr] + cc * dv[rr];
    W[r * 256 + c] = nw;
    if (last) WT2[((size_t)(r >> 3) * 256 + c) * 8 + (r & 7)] = f2bf(nw);
  }
}

// ---------------- GEMM: C[M,256] = A[M,KDIM](f32) * B(bf16, k-tiled) ----------------
// B layout: element (k, c) at ((k/8)*256 + c)*8 + k%8  (lane fragments = contiguous 16B)
// EPI==0: store bf16 output in the same k-tiled layout (output rows are the next GEMM's k)
// EPI==1: store f32 with relu to row-major [M,256]

__device__ __forceinline__ void cvt_store8(unsigned short* dst, float4 a0, float4 a1){
  union { bf16x8 v; unsigned short u[8]; } p;
  p.u[0] = f2bf(a0.x); p.u[1] = f2bf(a0.y); p.u[2] = f2bf(a0.z); p.u[3] = f2bf(a0.w);
  p.u[4] = f2bf(a1.x); p.u[5] = f2bf(a1.y); p.u[6] = f2bf(a1.z); p.u[7] = f2bf(a1.w);
  *reinterpret_cast<bf16x8*>(dst) = p.v;
}

template<int KDIM, int EPI>
__global__ __launch_bounds__(256) void kgemm(const float* __restrict__ A,
    const unsigned short* __restrict__ B, void* __restrict__ Cout){
  __shared__ unsigned short Alds[2][2048];   // 2 x [32 rows][64 cols] bf16, XOR-swizzled
  const int t = threadIdx.x;
  const int wave = t >> 6, lane = t & 63;
  const int bm = blockIdx.x;
  const int srow = t >> 3, scol = (t & 7) * 8;
  const float* aptr = A + (size_t)(bm * 32 + srow) * KDIM + scol;
  const int swoff = (srow * 64 + scol) ^ ((srow & 7) << 3);

  f32x4 acc[2][4];
  #pragma unroll
  for (int mf = 0; mf < 2; ++mf)
    #pragma unroll
    for (int nf = 0; nf < 4; ++nf){
      acc[mf][nf][0] = 0.f; acc[mf][nf][1] = 0.f; acc[mf][nf][2] = 0.f; acc[mf][nf][3] = 0.f;
    }

  // stage step 0
  {
    float4 a0 = *reinterpret_cast<const float4*>(aptr);
    float4 a1 = *reinterpret_cast<const float4*>(aptr + 4);
    cvt_store8(&Alds[0][swoff], a0, a1);
  }
  __syncthreads();

  constexpr int NS = KDIM / 64;
  int cur = 0;
  for (int s = 0; s < NS; ++s){
    float4 p0, p1;
    if (s + 1 < NS){
      p0 = *reinterpret_cast<const float4*>(aptr + (s + 1) * 64);
      p1 = *reinterpret_cast<const float4*>(aptr + (s + 1) * 64 + 4);
    }
    // B fragments: lane holds 8 contiguous k at col c
    bf16x8 bfr[2][4];
    #pragma unroll
    for (int ks = 0; ks < 2; ++ks)
      #pragma unroll
      for (int nf = 0; nf < 4; ++nf){
        int c  = (lane & 15) + nf * 16 + wave * 64;
        int kb = s * 8 + ks * 4 + (lane >> 4);
        bfr[ks][nf] = *reinterpret_cast<const bf16x8*>(B + ((size_t)kb * 256 + c) * 8);
      }
    // A fragments from LDS (swizzled)
    bf16x8 afr[2][2];
    #pragma unroll
    for (int ks = 0; ks < 2; ++ks)
      #pragma unroll
      for (int mf = 0; mf < 2; ++mf){
        int row = (lane & 15) + mf * 16;
        int kk  = ks * 32 + ((lane >> 4) << 3);
        int off = (row * 64 + kk) ^ ((row & 7) << 3);
        afr[ks][mf] = *reinterpret_cast<const bf16x8*>(&Alds[cur][off]);
      }
    #pragma unroll
    for (int ks = 0; ks < 2; ++ks)
      #pragma unroll
      for (int mf = 0; mf < 2; ++mf)
        #pragma unroll
        for (int nf = 0; nf < 4; ++nf)
          acc[mf][nf] = __builtin_amdgcn_mfma_f32_16x16x32_bf16(afr[ks][mf], bfr[ks][nf], acc[mf][nf], 0, 0, 0);
    if (s + 1 < NS)
      cvt_store8(&Alds[cur ^ 1][swoff], p0, p1);
    __syncthreads();
    cur ^= 1;
  }

  if constexpr (EPI == 0){
    unsigned short* H = reinterpret_cast<unsigned short*>(Cout);
    #pragma unroll
    for (int mf = 0; mf < 2; ++mf)
      #pragma unroll
      for (int nf = 0; nf < 4; ++nf){
        int c  = (lane & 15) + nf * 16 + wave * 64;
        int m0 = bm * 32 + mf * 16 + ((lane >> 4) << 2);
        union { bf16x4 v; unsigned short u[4]; } p;
        p.u[0] = f2bf(acc[mf][nf][0]);
        p.u[1] = f2bf(acc[mf][nf][1]);
        p.u[2] = f2bf(acc[mf][nf][2]);
        p.u[3] = f2bf(acc[mf][nf][3]);
        size_t off = ((size_t)(m0 >> 3) * 256 + c) * 8 + (m0 & 7);
        *reinterpret_cast<bf16x4*>(&H[off]) = p.v;
      }
  } else {
    float* O = reinterpret_cast<float*>(Cout);
    #pragma unroll
    for (int mf = 0; mf < 2; ++mf)
      #pragma unroll
      for (int nf = 0; nf < 4; ++nf){
        int c  = (lane & 15) + nf * 16 + wave * 64;
        int m0 = bm * 32 + mf * 16 + ((lane >> 4) << 2);
        #pragma unroll
        for (int j = 0; j < 4; ++j)
          O[(size_t)(m0 + j) * 256 + c] = fmaxf(acc[mf][nf][j], 0.0f);
      }
  }
}

// ---------------- launcher ----------------

extern "C" void kernel_launch(void* const* d_in, const int* in_sizes, int n_in,
                              void* d_out, int out_size, void* d_ws, size_t ws_size,
                              hipStream_t stream) {
  const float* x   = (const float*)d_in[0];   // [8192,512]
  const float* adj = (const float*)d_in[1];   // [8192,8192]
  const float* wt  = (const float*)d_in[2];   // [256,512]
  float* out = (float*)d_out;                 // [8192,256]

  char* ws = (char*)d_ws;
  float* n2            = (float*)ws;                                   // 4 B
  float* W             = (float*)(ws + 256);                           // 512*256*4
  float* G             = (float*)(ws + 256 + 524288);                  // 256*256*4
  unsigned short* WT2  = (unsigned short*)(ws + 256 + 524288 + 262144);            // 512*256*2
  unsigned short* HT2  = (unsigned short*)(ws + 256 + 524288 + 262144 + 262144);   // 8192*256*2

  hipMemsetAsync(n2, 0, 4, stream);
  knorm<<<128, 256, 0, stream>>>(wt, n2);
  kinit<<<256, 256, 0, stream>>>(wt, n2, W);

  // 6 quintic iterations: x <- a x + b x^3 + c x^5 (on singular values)
  const float ca[6] = { 4.2000f, 3.4445f, 1.875f, 1.875f, 1.875f, 1.875f };
  const float cb[6] = {-9.0000f, -4.7750f, -1.25f, -1.25f, -1.25f, -1.25f };
  const float cc[6] = {-6.8000f, 2.0315f, 0.375f, 0.375f, 0.375f, 0.375f };
  for (int it = 0; it < 6; ++it){
    kgram<<<dim3(16, 16), 256, 0, stream>>>(W, G);
    kupdate<<<128, 256, 0, stream>>>(W, G, ca[it], cb[it], cc[it], it == 5 ? 1 : 0, WT2);
  }

  // h^T (k-tiled bf16) = x @ W
  kgemm<512, 0><<<256, 256, 0, stream>>>(x, WT2, (void*)HT2);
  // out = relu(adj @ h)
  kgemm<8192, 1><<<256, 256, 0, stream>>>(adj, HT2, (void*)out);
}

// Round 2
// 246.008 us; speedup vs baseline: 2.7018x; 2.7018x over previous
//
#include <hip/hip_runtime.h>

typedef __attribute__((ext_vector_type(8))) short bf16x8;
typedef __attribute__((ext_vector_type(4))) short bf16x4;
typedef __attribute__((ext_vector_type(4))) float f32x4;

__device__ __forceinline__ unsigned short f2bf(float x){
  unsigned u = __float_as_uint(x);
  u = (u + 0x7fffu + ((u >> 16) & 1u)) >> 16;
  return (unsigned short)u;
}

// ---------------- Bjorck (polar factor) small kernels ----------------

// sum of squares of weight (131072 floats), atomic into *n2 (pre-zeroed)
__global__ __launch_bounds__(256) void knorm(const float* __restrict__ wt, float* __restrict__ n2){
  int t = blockIdx.x * 256 + threadIdx.x;
  float4 v = reinterpret_cast<const float4*>(wt)[t];
  float s = v.x*v.x + v.y*v.y + v.z*v.z + v.w*v.w;
  #pragma unroll
  for (int o = 32; o > 0; o >>= 1) s += __shfl_down(s, o, 64);
  __shared__ float red[4];
  if ((threadIdx.x & 63) == 0) red[threadIdx.x >> 6] = s;
  __syncthreads();
  if (threadIdx.x == 0) atomicAdd(n2, red[0] + red[1] + red[2] + red[3]);
}

// W[r][c] = weight[c][r] / (0.3 * ||weight||_F)   (W is 512x256 row-major)
__global__ __launch_bounds__(256) void kinit(const float* __restrict__ wt, const float* __restrict__ n2,
                                             float* __restrict__ W){
  int c = blockIdx.x;      // 0..255
  int r = threadIdx.x;     // 0..255 (+256)
  float s = rsqrtf(*n2) * (1.0f / 0.3f);
  W[(size_t)r * 256 + c]         = wt[(size_t)c * 512 + r] * s;
  W[(size_t)(r + 256) * 256 + c] = wt[(size_t)c * 512 + r + 256] * s;
}

// G += partial(W^T W): grid (8 j-tiles, 8 i-tiles, 8 k-parts), 32x32 tile, k-range 64
__global__ __launch_bounds__(256) void kgram2(const float* __restrict__ W, float* __restrict__ G){
  __shared__ __align__(16) float Wi[64][32];
  __shared__ __align__(16) float Wj[64][32];
  const int t = threadIdx.x;
  const int i0 = blockIdx.y * 32, j0 = blockIdx.x * 32, k0 = blockIdx.z * 64;
  const int lr = t >> 3, lc = (t & 7) * 4;
  #pragma unroll
  for (int p = 0; p < 2; ++p){
    int r = lr + p * 32;
    *reinterpret_cast<float4*>(&Wi[r][lc]) =
        *reinterpret_cast<const float4*>(&W[(size_t)(k0 + r) * 256 + i0 + lc]);
    *reinterpret_cast<float4*>(&Wj[r][lc]) =
        *reinterpret_cast<const float4*>(&W[(size_t)(k0 + r) * 256 + j0 + lc]);
  }
  __syncthreads();
  const int tx = t & 31, iy = t >> 5;
  float g0 = 0, g1 = 0, g2 = 0, g3 = 0;
  #pragma unroll 8
  for (int k = 0; k < 64; ++k){
    float wj = Wj[k][tx];
    float4 wi = *reinterpret_cast<const float4*>(&Wi[k][iy * 4]);
    g0 = fmaf(wi.x, wj, g0); g1 = fmaf(wi.y, wj, g1);
    g2 = fmaf(wi.z, wj, g2); g3 = fmaf(wi.w, wj, g3);
  }
  float* gp = &G[(size_t)(i0 + iy * 4) * 256 + j0 + tx];
  atomicAdd(gp,       g0); atomicAdd(gp + 256, g1);
  atomicAdd(gp + 512, g2); atomicAdd(gp + 768, g3);
}

// W <- ca*W + cb*(W G) + cc*(W G) G  ; block = 2 rows x 512 threads; zeroes Gnext
__global__ __launch_bounds__(512) void kupdate2(float* __restrict__ W, const float* __restrict__ G,
    float* __restrict__ Gnext, float ca, float cb, float cc, int last,
    unsigned short* __restrict__ WT2){
  __shared__ float wr[2][256], yl[2][256];
  const int t = threadIdx.x;
  const int c = t & 255, row = t >> 8;
  const int r = blockIdx.x * 2 + row;
  wr[row][c] = W[(size_t)r * 256 + c];
  __syncthreads();
  float y = 0;
  #pragma unroll 8
  for (int k = 0; k < 256; ++k)
    y = fmaf(wr[row][k], G[(size_t)k * 256 + c], y);
  yl[row][c] = y;
  __syncthreads();
  float d = 0;
  #pragma unroll 8
  for (int k = 0; k < 256; ++k)
    d = fmaf(yl[row][k], G[(size_t)k * 256 + c], d);
  float nw = ca * wr[row][c] + cb * y + cc * d;
  W[(size_t)r * 256 + c] = nw;
  if (r < 256) Gnext[(size_t)r * 256 + c] = 0.0f;   // pre-zero next iteration's G
  if (last) WT2[((size_t)(r >> 3) * 256 + c) * 8 + (r & 7)] = f2bf(nw);
}

// ---------------- GEMM: C[M,256] = A[M,KDIM](f32) * B(bf16, k-tiled) ----------------
// B layout: element (k, c) at ((k/8)*256 + c)*8 + k%8
// EPI==0: store bf16 output in same k-tiled layout (KS must be 1)
// EPI==1: fp32 atomicAdd into row-major [M,256] (caller pre-zeroes, relu afterwards)

__device__ __forceinline__ void cvt_store8(unsigned short* dst, float4 a0, float4 a1){
  union { bf16x8 v; unsigned short u[8]; } p;
  p.u[0] = f2bf(a0.x); p.u[1] = f2bf(a0.y); p.u[2] = f2bf(a0.z); p.u[3] = f2bf(a0.w);
  p.u[4] = f2bf(a1.x); p.u[5] = f2bf(a1.y); p.u[6] = f2bf(a1.z); p.u[7] = f2bf(a1.w);
  *reinterpret_cast<bf16x8*>(dst) = p.v;
}

template<int KDIM, int KS, int EPI>
__global__ __launch_bounds__(256) void kgemm(const float* __restrict__ A,
    const unsigned short* __restrict__ B, void* __restrict__ Cout){
  __shared__ unsigned short Alds[2][2048];   // 2 x [32 rows][64 cols] bf16, XOR-swizzled
  const int t = threadIdx.x;
  const int wave = t >> 6, lane = t & 63;
  const int bm = blockIdx.x;
  const int kp = blockIdx.y;
  constexpr int KLOC = KDIM / KS;
  constexpr int NS = KLOC / 64;
  const int kbase = kp * KLOC;
  const int srow = t >> 3, scol = (t & 7) * 8;
  const float* aptr = A + (size_t)(bm * 32 + srow) * KDIM + kbase + scol;
  const int swoff = (srow * 64 + scol) ^ ((srow & 7) << 3);

  f32x4 acc[2][4];
  #pragma unroll
  for (int mf = 0; mf < 2; ++mf)
    #pragma unroll
    for (int nf = 0; nf < 4; ++nf){
      acc[mf][nf][0] = 0.f; acc[mf][nf][1] = 0.f; acc[mf][nf][2] = 0.f; acc[mf][nf][3] = 0.f;
    }

  // stage step 0
  {
    float4 a0 = *reinterpret_cast<const float4*>(aptr);
    float4 a1 = *reinterpret_cast<const float4*>(aptr + 4);
    cvt_store8(&Alds[0][swoff], a0, a1);
  }
  __syncthreads();

  int cur = 0;
  for (int s = 0; s < NS; ++s){
    float4 p0, p1;
    if (s + 1 < NS){
      p0 = *reinterpret_cast<const float4*>(aptr + (s + 1) * 64);
      p1 = *reinterpret_cast<const float4*>(aptr + (s + 1) * 64 + 4);
    }
    // B fragments: lane holds 8 contiguous k at col c
    bf16x8 bfr[2][4];
    #pragma unroll
    for (int ks = 0; ks < 2; ++ks)
      #pragma unroll
      for (int nf = 0; nf < 4; ++nf){
        int c  = (lane & 15) + nf * 16 + wave * 64;
        int kb = (kbase >> 3) + s * 8 + ks * 4 + (lane >> 4);
        bfr[ks][nf] = *reinterpret_cast<const bf16x8*>(B + ((size_t)kb * 256 + c) * 8);
      }
    // A fragments from LDS (swizzled)
    bf16x8 afr[2][2];
    #pragma unroll
    for (int ks = 0; ks < 2; ++ks)
      #pragma unroll
      for (int mf = 0; mf < 2; ++mf){
        int row = (lane & 15) + mf * 16;
        int kk  = ks * 32 + ((lane >> 4) << 3);
        int off = (row * 64 + kk) ^ ((row & 7) << 3);
        afr[ks][mf] = *reinterpret_cast<const bf16x8*>(&Alds[cur][off]);
      }
    #pragma unroll
    for (int ks = 0; ks < 2; ++ks)
      #pragma unroll
      for (int mf = 0; mf < 2; ++mf)
        #pragma unroll
        for (int nf = 0; nf < 4; ++nf)
          acc[mf][nf] = __builtin_amdgcn_mfma_f32_16x16x32_bf16(afr[ks][mf], bfr[ks][nf], acc[mf][nf], 0, 0, 0);
    if (s + 1 < NS)
      cvt_store8(&Alds[cur ^ 1][swoff], p0, p1);
    __syncthreads();
    cur ^= 1;
  }

  if constexpr (EPI == 0){
    unsigned short* H = reinterpret_cast<unsigned short*>(Cout);
    #pragma unroll
    for (int mf = 0; mf < 2; ++mf)
      #pragma unroll
      for (int nf = 0; nf < 4; ++nf){
        int c  = (lane & 15) + nf * 16 + wave * 64;
        int m0 = bm * 32 + mf * 16 + ((lane >> 4) << 2);
        union { bf16x4 v; unsigned short u[4]; } p;
        p.u[0] = f2bf(acc[mf][nf][0]);
        p.u[1] = f2bf(acc[mf][nf][1]);
        p.u[2] = f2bf(acc[mf][nf][2]);
        p.u[3] = f2bf(acc[mf][nf][3]);
        size_t off = ((size_t)(m0 >> 3) * 256 + c) * 8 + (m0 & 7);
        *reinterpret_cast<bf16x4*>(&H[off]) = p.v;
      }
  } else {
    float* O = reinterpret_cast<float*>(Cout);
    #pragma unroll
    for (int mf = 0; mf < 2; ++mf)
      #pragma unroll
      for (int nf = 0; nf < 4; ++nf){
        int c  = (lane & 15) + nf * 16 + wave * 64;
        int m0 = bm * 32 + mf * 16 + ((lane >> 4) << 2);
        #pragma unroll
        for (int j = 0; j < 4; ++j)
          atomicAdd(&O[(size_t)(m0 + j) * 256 + c], acc[mf][nf][j]);
      }
  }
}

__global__ __launch_bounds__(256) void krelu(float* __restrict__ O){
  int i = blockIdx.x * 256 + threadIdx.x;
  float4 v = reinterpret_cast<float4*>(O)[i];
  v.x = fmaxf(v.x, 0.f); v.y = fmaxf(v.y, 0.f);
  v.z = fmaxf(v.z, 0.f); v.w = fmaxf(v.w, 0.f);
  reinterpret_cast<float4*>(O)[i] = v;
}

// ---------------- launcher ----------------

extern "C" void kernel_launch(void* const* d_in, const int* in_sizes, int n_in,
                              void* d_out, int out_size, void* d_ws, size_t ws_size,
                              hipStream_t stream) {
  const float* x   = (const float*)d_in[0];   // [8192,512]
  const float* adj = (const float*)d_in[1];   // [8192,8192]
  const float* wt  = (const float*)d_in[2];   // [256,512]
  float* out = (float*)d_out;                 // [8192,256]

  char* ws = (char*)d_ws;
  float* n2            = (float*)ws;                               // 4 B
  float* W             = (float*)(ws + 4096);                      // 512*256*4 = 524288
  float* G0            = (float*)(ws + 4096 + 524288);             // 256 KB
  float* G1            = (float*)(ws + 4096 + 524288 + 262144);    // 256 KB
  unsigned short* WT2  = (unsigned short*)(ws + 4096 + 524288 + 2*262144);            // 256 KB
  unsigned short* HT2  = (unsigned short*)(ws + 4096 + 524288 + 3*262144);            // 4 MB

  hipMemsetAsync(n2, 0, 4, stream);
  hipMemsetAsync(G0, 0, 262144, stream);
  hipMemsetAsync(out, 0, (size_t)8192 * 256 * 4, stream);

  knorm<<<128, 256, 0, stream>>>(wt, n2);
  kinit<<<256, 256, 0, stream>>>(wt, n2, W);

  // 5 iterations: aggressive quintic, Muon quintic, then 3 exact Bjorck steps
  const float ca[5] = { 4.2000f, 3.4445f, 1.875f, 1.875f, 1.875f };
  const float cb[5] = {-9.0000f, -4.7750f, -1.25f, -1.25f, -1.25f };
  const float cc[5] = {-6.8000f, 2.0315f, 0.375f, 0.375f, 0.375f };
  float* Gb[2] = {G0, G1};
  for (int it = 0; it < 5; ++it){
    float* Gc = Gb[it & 1];
    float* Gn = Gb[(it + 1) & 1];
    kgram2<<<dim3(8, 8, 8), 256, 0, stream>>>(W, Gc);
    kupdate2<<<256, 512, 0, stream>>>(W, Gc, Gn, ca[it], cb[it], cc[it], it == 4 ? 1 : 0, WT2);
  }

  // h^T (k-tiled bf16) = x @ W
  kgemm<512, 1, 0><<<dim3(256, 1), 256, 0, stream>>>(x, WT2, (void*)HT2);
  // out += adj @ h  (k-split 4, fp32 atomics), then relu
  kgemm<8192, 4, 1><<<dim3(256, 4), 256, 0, stream>>>(adj, HT2, (void*)out);
  krelu<<<2048, 256, 0, stream>>>(out);
}